// Round 10
// baseline (51.075 us; speedup 1.0000x reference)
//
#include <hip/hip_runtime.h>

#define LSTEPS 64
#define NF 512
#define MB 2048
#define CSTRIDE 256   // padded per-step pair stride for cA/cB (in float4-pairs)
#define PL (NF * NF)  // bf16 elements per 512x512 plane
#define LDT 72

typedef __attribute__((ext_vector_type(8))) short bf16x8;
typedef __attribute__((ext_vector_type(4))) float f32x4;
typedef __attribute__((ext_vector_type(4))) int i32x4;

__device__ __forceinline__ float2 cmul(float2 a, float2 b) {
  return make_float2(fmaf(a.x, b.x, -(a.y * b.y)), fmaf(a.x, b.y, a.y * b.x));
}
__device__ __forceinline__ float2 cfma(float2 a, float2 b, float2 c) {
  return make_float2(fmaf(a.x, b.x, fmaf(-a.y, b.y, c.x)),
                     fmaf(a.x, b.y, fmaf(a.y, b.x, c.y)));
}
__device__ __forceinline__ unsigned short f2bf(float f) {
  union { float f; unsigned u; } v; v.f = f;
  unsigned r = v.u + 0x7FFF + ((v.u >> 16) & 1);
  return (unsigned short)(r >> 16);
}

// ---------------- K1: coeffs (incl. cB pad zero) + X->bf16 planes (R6-proven) ----------------
__global__ __launch_bounds__(256) void prep_kernel(
    const float* __restrict__ a0, const float* __restrict__ a1,
    const float* __restrict__ b0, const float* __restrict__ b1,
    const float4* __restrict__ Xf,
    float4* __restrict__ cA, float4* __restrict__ cB,
    unsigned short* __restrict__ Xr, unsigned short* __restrict__ Xi)
{
  const int bid = blockIdx.x, tid = threadIdx.x;
  if (bid < 64) {
    const int l = bid;
    {
      float ang0 = a0[l * 256 + tid], ang1 = a1[l * 256 + tid];
      float se, ce, st, ct;
      sincosf(ang0, &se, &ce);
      sincosf(ang1, &st, &ct);
      float2 ephi = make_float2(ce, se);
      float2 tt = make_float2(0.5f * (ct - 1.0f), 0.5f * st);
      float2 uu = make_float2(0.5f * (ct + 1.0f), 0.5f * st);
      float2 C1 = cmul(ephi, tt);
      float2 C2 = make_float2(-uu.y, uu.x);
      float2 eu = cmul(ephi, uu);
      float2 C3 = make_float2(-eu.y, eu.x);
      float2 C4 = make_float2(-tt.x, -tt.y);
      float4* dst = cA + (size_t)(l * CSTRIDE + tid) * 2;
      dst[0] = make_float4(C1.x, C1.y, C2.x, C2.y);
      dst[1] = make_float4(C3.x, C3.y, C4.x, C4.y);
    }
    if (tid < 255) {
      float ang0 = b0[l * 255 + tid], ang1 = b1[l * 255 + tid];
      float se, ce, st, ct;
      sincosf(ang0, &se, &ce);
      sincosf(ang1, &st, &ct);
      float2 ephi = make_float2(ce, se);
      float2 tt = make_float2(0.5f * (ct - 1.0f), 0.5f * st);
      float2 uu = make_float2(0.5f * (ct + 1.0f), 0.5f * st);
      float2 C1 = cmul(ephi, tt);
      float2 C2 = make_float2(-uu.y, uu.x);
      float2 eu = cmul(ephi, uu);
      float2 C3 = make_float2(-eu.y, eu.x);
      float2 C4 = make_float2(-tt.x, -tt.y);
      float4* dst = cB + (size_t)(l * CSTRIDE + tid) * 2;
      dst[0] = make_float4(C1.x, C1.y, C2.x, C2.y);
      dst[1] = make_float4(C3.x, C3.y, C4.x, C4.y);
    } else {
      float4* dst = cB + (size_t)(l * CSTRIDE + 255) * 2;
      dst[0] = make_float4(0.f, 0.f, 0.f, 0.f);
      dst[1] = make_float4(0.f, 0.f, 0.f, 0.f);
    }
  } else {
    const int qi = (bid - 64) * 256 + tid;       // 0..262143
    float4 v0 = Xf[(size_t)qi * 2];
    float4 v1 = Xf[(size_t)qi * 2 + 1];
    ushort4 r, im;
    r.x = f2bf(v0.x); im.x = f2bf(v0.y);
    r.y = f2bf(v0.z); im.y = f2bf(v0.w);
    r.z = f2bf(v1.x); im.z = f2bf(v1.y);
    r.w = f2bf(v1.z); im.w = f2bf(v1.w);
    *(ushort4*)(Xr + (size_t)qi * 4) = r;
    *(ushort4*)(Xi + (size_t)qi * 4) = im;
  }
}

// ---------------- K2: 4 chunks x 16 steps, 2 cols/wave, full-column normal writes ----------------
struct MZS { float2 a0, b0, a1, b1; };

__device__ __forceinline__ void mzi_apply(const float4& k0, const float4& k1,
                                          float2& a, float2& b) {
  float2 c1 = make_float2(k0.x, k0.y), c2 = make_float2(k0.z, k0.w);
  float2 c3 = make_float2(k1.x, k1.y), c4 = make_float2(k1.z, k1.w);
  float2 na = cfma(c2, b, cmul(c1, a));
  float2 nb = cfma(c4, b, cmul(c3, a));
  a = na; b = nb;
}
__device__ __forceinline__ float2 mzi_bnd(const float4& k0, const float4& k1,
                                          float2& a, float2 b, bool en) {
  float2 d1 = make_float2(k0.x, k0.y), d2 = make_float2(k0.z, k0.w);
  float2 d3 = make_float2(k1.x, k1.y), d4 = make_float2(k1.z, k1.w);
  float2 na = cfma(d2, b, cmul(d1, a));
  float2 nb = cfma(d4, b, cmul(d3, a));
  if (en) a = na;
  return en ? nb : make_float2(0.f, 0.f);
}
__device__ __forceinline__ void load_bank(float4 (&K)[8],
    const float4* __restrict__ cA, const float4* __restrict__ cB, int l, int q0)
{
  const float4* pa = cA + (size_t)l * (CSTRIDE * 2) + (size_t)q0 * 2;
  const float4* pb = cB + (size_t)l * (CSTRIDE * 2) + (size_t)q0 * 2;
  K[0] = pa[0]; K[1] = pa[1]; K[2] = pa[2]; K[3] = pa[3];
  K[4] = pb[0]; K[5] = pb[1]; K[6] = pb[2]; K[7] = pb[3];
}
__device__ __forceinline__ void step_state(const float4 (&K)[8], int L, bool hasBnd,
                                           MZS& s)
{
  mzi_apply(K[0], K[1], s.a0, s.b0);
  mzi_apply(K[2], K[3], s.a1, s.b1);
  float xnx = __shfl_down(s.a0.x, 1);
  float xny = __shfl_down(s.a0.y, 1);
  float2 xn = (L == 63) ? make_float2(0.f, 0.f) : make_float2(xnx, xny);
  float2 nbo = mzi_bnd(K[6], K[7], s.b1, xn, hasBnd);
  mzi_apply(K[4], K[5], s.b0, s.a1);
  float px = __shfl_up(nbo.x, 1);
  float py = __shfl_up(nbo.y, 1);
  if (L > 0) s.a0 = make_float2(px, py);
}

__global__ __launch_bounds__(64) void chunk_mesh(
    const float4* __restrict__ cA, const float4* __restrict__ cB,
    unsigned short* __restrict__ Cb)     // 4 chunks x [re PL][im PL]
{
  const int bid = blockIdx.x;                  // 0..1023
  const int m = bid >> 8;                      // chunk (steps 16m..16m+15)
  const int cb = bid & 255;
  const int c = (cb & 7) * 32 + (cb >> 3);     // bijective XCD swizzle
  const int L = threadIdx.x;
  int ws = c - 63; ws = ws < 0 ? 0 : (ws > 128 ? 128 : ws);
  const int q0 = ws + 2 * L, q1 = q0 + 1;
  const bool hasBnd = (q1 < 255);

  MZS s0, s1;   // columns j0=2c (impulse row 2c) and j1=2c+1 (impulse row 2c+1)
  s0.a0 = make_float2((q0 == c) ? 1.f : 0.f, 0.f);
  s0.b0 = make_float2(0.f, 0.f);
  s0.a1 = make_float2((q1 == c) ? 1.f : 0.f, 0.f);
  s0.b1 = make_float2(0.f, 0.f);
  s1.a0 = make_float2(0.f, 0.f);
  s1.b0 = make_float2((q0 == c) ? 1.f : 0.f, 0.f);
  s1.a1 = make_float2(0.f, 0.f);
  s1.b1 = make_float2((q1 == c) ? 1.f : 0.f, 0.f);

  const int l0 = m * 16;
  float4 K0[8], K1[8];
  load_bank(K0, cA, cB, l0 + 0, q0);
  load_bank(K1, cA, cB, l0 + 1, q0);
#pragma unroll 1
  for (int i = 0; i < 14; i += 2) {
    step_state(K0, L, hasBnd, s0); step_state(K0, L, hasBnd, s1);
    load_bank(K0, cA, cB, l0 + ((i + 2 < 16) ? i + 2 : 15), q0);
    step_state(K1, L, hasBnd, s0); step_state(K1, L, hasBnd, s1);
    load_bank(K1, cA, cB, l0 + ((i + 3 < 16) ? i + 3 : 15), q0);
  }
  step_state(K0, L, hasBnd, s0); step_state(K0, L, hasBnd, s1);   // step 14
  step_state(K1, L, hasBnd, s0); step_state(K1, L, hasBnd, s1);   // step 15

  // full-column packed writes (R6-proven): chunk factor C_m[row][col]
  unsigned* nr32 = (unsigned*)(Cb + (size_t)m * 2 * PL);
  unsigned* ni32 = nr32 + PL / 2;
  const int rows[4] = {2 * q0, 2 * q0 + 1, 2 * q1, 2 * q1 + 1};
  const float2 v0[4] = {s0.a0, s0.b0, s0.a1, s0.b1};
  const float2 v1[4] = {s1.a0, s1.b0, s1.a1, s1.b1};
#pragma unroll
  for (int e = 0; e < 4; ++e) {
    unsigned pr = (unsigned)f2bf(v0[e].x) | ((unsigned)f2bf(v1[e].x) << 16);
    unsigned pi = (unsigned)f2bf(v0[e].y) | ((unsigned)f2bf(v1[e].y) << 16);
    nr32[(size_t)rows[e] * (NF / 2) + c] = pr;
    ni32[(size_t)rows[e] * (NF / 2) + c] = pi;
  }
#pragma unroll
  for (int e = 0; e < 4; ++e) {
    const int row = (2 * ws + 256 + 4 * L + e) & 511;   // 256-row complement
    nr32[(size_t)row * (NF / 2) + c] = 0u;
    ni32[(size_t)row * (NF / 2) + c] = 0u;
  }
}

// ---------------- banded batch GEMM: Z'[r][n] = sum_j Z[r][j] * C[n][j]  (band |n-j|<=33) ----------------
template <bool FINAL>
__global__ __launch_bounds__(256) void gemm_kernel(
    const unsigned short* __restrict__ Zr, const unsigned short* __restrict__ Zi,
    const unsigned short* __restrict__ Cr, const unsigned short* __restrict__ Ci,
    unsigned short* __restrict__ Or, unsigned short* __restrict__ Oi,
    const float* __restrict__ omega, float2* __restrict__ Y)
{
  __shared__ __align__(16) unsigned short Ars[32][LDT];
  __shared__ __align__(16) unsigned short Ais[32][LDT];
  __shared__ __align__(16) unsigned short Brs[64][LDT];
  __shared__ __align__(16) unsigned short Bis[64][LDT];

  const int tid = threadIdx.x;
  const int w = tid >> 6, wm = w & 1, wn = w >> 1;
  const int lane = tid & 63;
  const int bm = (blockIdx.x >> 3) * 32;
  const int bn = (blockIdx.x & 7) * 64;

  int klo = bn - 40; if (klo < 0) klo = 0; klo &= ~63;
  int khi = bn + 104; if (khi > NF) khi = NF; khi = (khi + 63) & ~63;

  f32x4 acc_r[2], acc_i[2];
#pragma unroll
  for (int nf = 0; nf < 2; ++nf) {
    acc_r[nf] = (f32x4){0.f, 0.f, 0.f, 0.f};
    acc_i[nf] = (f32x4){0.f, 0.f, 0.f, 0.f};
  }
  const int sar = tid >> 3, sak = (tid & 7) * 8;
  const int sbr = tid >> 2, sbk = (tid & 3) * 16;

  for (int k0 = klo; k0 < khi; k0 += 64) {
    const uint4* gar = (const uint4*)(Zr + (size_t)(bm + sar) * NF + k0 + sak);
    const uint4* gai = (const uint4*)(Zi + (size_t)(bm + sar) * NF + k0 + sak);
    const uint4* gbr = (const uint4*)(Cr + (size_t)(bn + sbr) * NF + k0 + sbk);
    const uint4* gbi = (const uint4*)(Ci + (size_t)(bn + sbr) * NF + k0 + sbk);
    uint4 ar = gar[0];
    uint4 ai = gai[0];
    uint4 br0 = gbr[0], br1 = gbr[1];
    uint4 bi0 = gbi[0], bi1 = gbi[1];

    if (k0 > klo) __syncthreads();

    *(uint4*)&Ars[sar][sak]     = ar;
    *(uint4*)&Ais[sar][sak]     = ai;
    *(uint4*)&Brs[sbr][sbk]     = br0;
    *(uint4*)&Brs[sbr][sbk + 8] = br1;
    *(uint4*)&Bis[sbr][sbk]     = bi0;
    *(uint4*)&Bis[sbr][sbk + 8] = bi1;

    __syncthreads();

#pragma unroll
    for (int kk = 0; kk < 2; ++kk) {
      const int ko = kk * 32 + (lane >> 4) * 8;
      bf16x8 afr = *(const bf16x8*)&Ars[wm * 16 + (lane & 15)][ko];
      bf16x8 afi = *(const bf16x8*)&Ais[wm * 16 + (lane & 15)][ko];
      i32x4 neg = (i32x4)afi ^ (int)0x80008000;
      bf16x8 afin = (bf16x8)neg;     // -Ai
#pragma unroll
      for (int nf = 0; nf < 2; ++nf) {
        bf16x8 bfr = *(const bf16x8*)&Brs[wn * 32 + nf * 16 + (lane & 15)][ko];
        bf16x8 bfi = *(const bf16x8*)&Bis[wn * 32 + nf * 16 + (lane & 15)][ko];
        acc_r[nf] = __builtin_amdgcn_mfma_f32_16x16x32_bf16(afr,  bfr, acc_r[nf], 0, 0, 0);
        acc_r[nf] = __builtin_amdgcn_mfma_f32_16x16x32_bf16(afin, bfi, acc_r[nf], 0, 0, 0);
        acc_i[nf] = __builtin_amdgcn_mfma_f32_16x16x32_bf16(afr,  bfi, acc_i[nf], 0, 0, 0);
        acc_i[nf] = __builtin_amdgcn_mfma_f32_16x16x32_bf16(afi,  bfr, acc_i[nf], 0, 0, 0);
      }
    }
  }

  const int dn0 = bn + wn * 32 + (lane & 15);
  const int dm0 = bm + wm * 16 + (lane >> 4) * 4;
#pragma unroll
  for (int nf = 0; nf < 2; ++nf) {
    const int n = dn0 + nf * 16;
    if (FINAL) {
      float sn, cn;
      sincosf(omega[n], &sn, &cn);
#pragma unroll
      for (int r = 0; r < 4; ++r) {
        float yr = acc_r[nf][r], yi = acc_i[nf][r];
        Y[(size_t)(dm0 + r) * NF + n] =
            make_float2(fmaf(yr, cn, -(yi * sn)), fmaf(yr, sn, yi * cn));
      }
    } else {
#pragma unroll
      for (int r = 0; r < 4; ++r) {
        Or[(size_t)(dm0 + r) * NF + n] = f2bf(acc_r[nf][r]);
        Oi[(size_t)(dm0 + r) * NF + n] = f2bf(acc_i[nf][r]);
      }
    }
  }
}

extern "C" void kernel_launch(void* const* d_in, const int* in_sizes, int n_in,
                              void* d_out, int out_size, void* d_ws, size_t ws_size,
                              hipStream_t stream) {
  const float* cmplx = (const float*)d_in[0];
  const float* a0    = (const float*)d_in[1];
  const float* a1    = (const float*)d_in[2];
  const float* b0    = (const float*)d_in[3];
  const float* b1    = (const float*)d_in[4];
  const float* omega = (const float*)d_in[5];

  size_t off = 0;
  float4* cA = (float4*)((char*)d_ws + off); off += (size_t)LSTEPS * CSTRIDE * 2 * sizeof(float4);
  float4* cB = (float4*)((char*)d_ws + off); off += (size_t)LSTEPS * CSTRIDE * 2 * sizeof(float4);
  unsigned short* Xr = (unsigned short*)((char*)d_ws + off); off += (size_t)MB * NF * 2;
  unsigned short* Xi = (unsigned short*)((char*)d_ws + off); off += (size_t)MB * NF * 2;
  unsigned short* Cb = (unsigned short*)((char*)d_ws + off); off += (size_t)4 * 2 * PL * 2;
  unsigned short* Z1r = (unsigned short*)((char*)d_ws + off); off += (size_t)MB * NF * 2;
  unsigned short* Z1i = (unsigned short*)((char*)d_ws + off); off += (size_t)MB * NF * 2;
  unsigned short* Z2r = (unsigned short*)((char*)d_ws + off); off += (size_t)MB * NF * 2;
  unsigned short* Z2i = (unsigned short*)((char*)d_ws + off); off += (size_t)MB * NF * 2;
  float2* Y = (float2*)d_out;

  prep_kernel<<<1088, 256, 0, stream>>>(a0, a1, b0, b1, (const float4*)cmplx,
                                        cA, cB, Xr, Xi);
  chunk_mesh<<<1024, 64, 0, stream>>>(cA, cB, Cb);

  const unsigned short* C0r = Cb;               const unsigned short* C0i = Cb + PL;
  const unsigned short* C1r = Cb + 2 * PL;      const unsigned short* C1i = Cb + 3 * PL;
  const unsigned short* C2r = Cb + 4 * PL;      const unsigned short* C2i = Cb + 5 * PL;
  const unsigned short* C3r = Cb + 6 * PL;      const unsigned short* C3i = Cb + 7 * PL;

  const int grid = (MB / 32) * (NF / 64);       // 512 blocks
  gemm_kernel<false><<<grid, 256, 0, stream>>>(Xr,  Xi,  C0r, C0i, Z1r, Z1i, omega, Y);
  gemm_kernel<false><<<grid, 256, 0, stream>>>(Z1r, Z1i, C1r, C1i, Z2r, Z2i, omega, Y);
  gemm_kernel<false><<<grid, 256, 0, stream>>>(Z2r, Z2i, C2r, C2i, Z1r, Z1i, omega, Y);
  gemm_kernel<true> <<<grid, 256, 0, stream>>>(Z1r, Z1i, C3r, C3i, Z2r, Z2i, omega, Y);
}